// Round 14
// baseline (206.351 us; speedup 1.0000x reference)
//
#include <hip/hip_runtime.h>
#include <hip/hip_bf16.h>

#define T_TOK 2048
#define E_DIM 1024
#define F_DIM 2048
#define N_EXP 8

typedef __attribute__((ext_vector_type(8))) short short8;
typedef __attribute__((ext_vector_type(4))) float f32x4;

__device__ __forceinline__ short bf2s(__hip_bfloat16 v) {
  union { __hip_bfloat16 b; short s; } u; u.b = v; return u.s;
}

__device__ __forceinline__ void gload_lds16(const void* g, void* l) {
  __builtin_amdgcn_global_load_lds((const __attribute__((address_space(1))) void*)g,
                                   (__attribute__((address_space(3))) void*)l, 16, 0, 0);
}

// ---- r4-proven 64x64 transpose tile: fp32 LDS stride 65, <=2-way banks both ways ----
__device__ __forceinline__ void transpose_tile65(const float* __restrict__ src,
                                                 __hip_bfloat16* __restrict__ dst,
                                                 int C, int R, int r0, int c0,
                                                 int tt, float* lt) {
#pragma unroll
  for (int i = 0; i < 4; i++) {
    int chunk = i * 256 + tt;
    int r = chunk >> 4, c4 = (chunk & 15) * 4;
    float4 v = *(const float4*)(src + (size_t)(r0 + r) * C + c0 + c4);
    float* p = &lt[r * 65 + c4];
    p[0] = v.x; p[1] = v.y; p[2] = v.z; p[3] = v.w;
  }
  __syncthreads();
#pragma unroll
  for (int i = 0; i < 2; i++) {
    int chunk = i * 256 + tt;
    int c = chunk >> 3, rr = (chunk & 7) * 8;
    short8 o;
#pragma unroll
    for (int j = 0; j < 8; j++) o[j] = bf2s(__float2bfloat16(lt[(rr + j) * 65 + c]));
    *(short8*)(dst + (size_t)(c0 + c) * R + r0 + rr) = o;
  }
}

// ---------------- prep: riders first (router 512, convert 512), then 2048 persistent
// transpose workers, each pipelining 4 tiles through double-buffered stride-65 LDS ----
__global__ __launch_bounds__(256) void prep_kernel(const float* __restrict__ w0,
                                                   const float* __restrict__ w1,
                                                   const float* __restrict__ x,
                                                   const float* __restrict__ gk,
                                                   __hip_bfloat16* __restrict__ w0t,
                                                   __hip_bfloat16* __restrict__ w1t,
                                                   __hip_bfloat16* __restrict__ xb,
                                                   int* __restrict__ tk_e,
                                                   float* __restrict__ tk_p,
                                                   int* __restrict__ counts) {
  __shared__ float lt[2][64 * 65];
  int bid = blockIdx.x;
  int tid = threadIdx.x;

  if (bid >= 1024) {
    // persistent transpose worker: 4 tiles, one E-row-band, marching across F columns
    int w = bid - 1024;                 // 0..2047
    int which = w >> 10;
    int rem = w & 1023;
    int e = rem >> 7;                   // 0..7
    int rt = (rem >> 3) & 15;           // E tile 0..15
    int cq = rem & 7;                   // F quad 0..7
    const float* src = (which ? w1 : w0) + (size_t)e * E_DIM * F_DIM;
    __hip_bfloat16* dst = (which ? w1t : w0t) + (size_t)e * E_DIM * F_DIM;
    int r0 = rt * 64;

    float4 v[4];
    auto loadT = [&](int i) {
      int c0 = (cq * 4 + i) * 64;
#pragma unroll
      for (int k = 0; k < 4; k++) {
        int chunk = k * 256 + tid;
        int r = chunk >> 4, c4 = (chunk & 15) * 4;
        v[k] = *(const float4*)(src + (size_t)(r0 + r) * F_DIM + c0 + c4);
      }
    };
    auto wrLDS = [&](int b) {
#pragma unroll
      for (int k = 0; k < 4; k++) {
        int chunk = k * 256 + tid;
        int r = chunk >> 4, c4 = (chunk & 15) * 4;
        float* p = &lt[b][r * 65 + c4];
        p[0] = v[k].x; p[1] = v[k].y; p[2] = v[k].z; p[3] = v[k].w;
      }
    };
    auto stphase = [&](int b, int i) {
      int c0 = (cq * 4 + i) * 64;
#pragma unroll
      for (int k = 0; k < 2; k++) {
        int chunk = k * 256 + tid;
        int c = chunk >> 3, rr = (chunk & 7) * 8;
        short8 o;
#pragma unroll
        for (int j = 0; j < 8; j++) o[j] = bf2s(__float2bfloat16(lt[b][(rr + j) * 65 + c]));
        *(short8*)(dst + (size_t)(c0 + c) * E_DIM + r0 + rr) = o;
      }
    };

    loadT(0);
    wrLDS(0);
#pragma unroll
    for (int i = 0; i < 4; i++) {
      int b = i & 1;
      if (i < 3) loadT(i + 1);       // next tile's loads in flight under store phase
      __syncthreads();               // buffer b fully written
      stphase(b, i);
      if (i < 3) wrLDS(b ^ 1);       // land loads into the other buffer
    }
    return;
  }

  if (bid >= 512) {
    // convert_x: 512 blocks x 2 passes
    int idx = bid - 512;
#pragma unroll
    for (int pass = 0; pass < 2; ++pass) {
      size_t i = (size_t)idx * 4096 + pass * 2048 + tid * 8;
      float4 a = *(const float4*)(x + i);
      float4 b = *(const float4*)(x + i + 4);
      short8 oo;
      oo[0] = bf2s(__float2bfloat16(a.x)); oo[1] = bf2s(__float2bfloat16(a.y));
      oo[2] = bf2s(__float2bfloat16(a.z)); oo[3] = bf2s(__float2bfloat16(a.w));
      oo[4] = bf2s(__float2bfloat16(b.x)); oo[5] = bf2s(__float2bfloat16(b.y));
      oo[6] = bf2s(__float2bfloat16(b.z)); oo[7] = bf2s(__float2bfloat16(b.w));
      *(short8*)(xb + i) = oo;
    }
    return;
  }

  // router: fp64 logits, top-2, softmax
  int w = tid >> 6, l = tid & 63;
  int t = bid * 4 + w;
  const float* xr = x + (size_t)t * E_DIM;
  double acc[N_EXP];
#pragma unroll
  for (int n = 0; n < N_EXP; n++) acc[n] = 0.0;
  for (int j = 0; j < 16; j++) {
    int i = j * 64 + l;
    double xv = (double)xr[i];
    const float* g = gk + (size_t)i * N_EXP;
#pragma unroll
    for (int n = 0; n < N_EXP; n++) acc[n] += xv * (double)g[n];
  }
#pragma unroll
  for (int off = 32; off > 0; off >>= 1) {
#pragma unroll
    for (int n = 0; n < N_EXP; n++) acc[n] += __shfl_down(acc[n], off);
  }
  if (l == 0) {
    int e1 = 0; double v1 = acc[0];
    for (int n = 1; n < N_EXP; n++) if (acc[n] > v1) { v1 = acc[n]; e1 = n; }
    int e2 = -1; double v2 = -1e300;
    for (int n = 0; n < N_EXP; n++) if (n != e1 && acc[n] > v2) { v2 = acc[n]; e2 = n; }
    float ex = __expf((float)(v2 - v1));     // <= 1
    float p1 = 1.f / (1.f + ex);
    float p2 = ex / (1.f + ex);
    tk_e[t * 2 + 0] = e1; tk_p[t * 2 + 0] = p1;
    tk_e[t * 2 + 1] = e2; tk_p[t * 2 + 1] = p2;
    atomicAdd(&counts[e1], 1);
    atomicAdd(&counts[e2], 1);
  }
}

// ---------------- scan + permute, single block ----------------
__global__ __launch_bounds__(256) void scanperm_kernel(const int* __restrict__ tk_e,
                                                       const float* __restrict__ tk_p,
                                                       int* __restrict__ ctrl,
                                                       int* __restrict__ slot_tok,
                                                       float* __restrict__ slot_prob,
                                                       int* __restrict__ inv) {
  __shared__ int offs[8], cur[8];
  int tid = threadIdx.x;
  if (tid == 0) {
    int off = 0, idx = 0;
    for (int e = 0; e < N_EXP; e++) {
      offs[e] = off; cur[e] = 0;
      int c = ctrl[e];
      for (int m0 = 0; m0 < c; m0 += 128) {
        ctrl[32 + idx] = e;
        ctrl[96 + idx] = off + m0;
        ctrl[160 + idx] = (c - m0 < 128) ? (c - m0) : 128;
        idx++;
      }
      off += c;
    }
    ctrl[24] = idx;
  }
  __syncthreads();
  for (int g = tid; g < 2 * T_TOK; g += 256) {
    int e = tk_e[g];
    float p = tk_p[g];
    int pos = atomicAdd(&cur[e], 1);
    int slot = offs[e] + pos;
    slot_tok[slot] = g >> 1;
    slot_prob[slot] = p;
    inv[g] = slot;
  }
}

// ---------------- GEMM1 (+embedded wo transpose): h = silu(X@w0)*(X@w1) ----------------
// gemm: blocks [0,1280): BM=128 BN=64 BK=64, 8 waves (4m x 2n), 32KB LDS, 4 blk/CU
// transpose: blocks [1280,3328): wo [F][E]fp32 -> wot [E][F]bf16, 2x 64x64 tiles/block
__global__ __launch_bounds__(512, 4) void gemm1_kernel(const __hip_bfloat16* __restrict__ xb,
                                                       const __hip_bfloat16* __restrict__ w0t,
                                                       const __hip_bfloat16* __restrict__ w1t,
                                                       const int* __restrict__ ctrl,
                                                       const int* __restrict__ slot_tok,
                                                       __hip_bfloat16* __restrict__ h,
                                                       const float* __restrict__ wo,
                                                       __hip_bfloat16* __restrict__ wot) {
  __shared__ float ltf[2][64 * 65];            // 33,280 B union
  short* lA  = (short*)&ltf[0][0];             // 8192 shorts (16 KB)
  short* lB0 = lA + 8192;                      // 4096 shorts (8 KB)
  short* lB1 = lA + 12288;                     // 4096 shorts (8 KB)

  if (blockIdx.x >= 1280) {
    int half = threadIdx.x >> 8, tt = threadIdx.x & 255;
    int tile = (blockIdx.x - 1280) * 2 + half;    // 0..4095
    int e = tile >> 9;
    int t2 = tile & 511;
    int r0 = (t2 & 31) * 64;        // F tiles
    int c0 = (t2 >> 5) * 64;        // E tiles
    transpose_tile65(wo + (size_t)e * F_DIM * E_DIM, wot + (size_t)e * E_DIM * F_DIM,
                     E_DIM, F_DIM, r0, c0, tt, &ltf[half][0]);
    return;
  }

  int lin = blockIdx.x;                         // 1280 = 8 * 160
  int logical = (lin & 7) * 160 + (lin >> 3);   // XCD-chunked
  int mt = logical % 40;
  int fy = logical / 40;                        // 0..31
  if (mt >= ctrl[24]) return;
  int e = ctrl[32 + mt];
  int slot0 = ctrl[96 + mt];
  int rowsv = ctrl[160 + mt];
  int f0 = fy * 64;

  int tid = threadIdx.x;
  int w = tid >> 6, l = tid & 63;
  int wm = w >> 1, wn = w & 1;
  int frow = l & 15, fk = l >> 4;

  int r1 = tid >> 3;
  int kc = ((tid & 7) ^ (r1 & 7)) * 8;
  int tokA1 = slot_tok[slot0 + r1];
  int tokA2 = slot_tok[slot0 + r1 + 64];
  const __hip_bfloat16* aS1 = xb + (size_t)tokA1 * E_DIM + kc;
  const __hip_bfloat16* aS2 = xb + (size_t)tokA2 * E_DIM + kc;
  const __hip_bfloat16* b0S = w0t + ((size_t)e * F_DIM + f0 + r1) * E_DIM + kc;
  const __hip_bfloat16* b1S = w1t + ((size_t)e * F_DIM + f0 + r1) * E_DIM + kc;

  f32x4 zero4 = {0.f, 0.f, 0.f, 0.f};
  f32x4 acc0[2][2], acc1[2][2];
#pragma unroll
  for (int mi = 0; mi < 2; mi++)
#pragma unroll
    for (int ni = 0; ni < 2; ni++) { acc0[mi][ni] = zero4; acc1[mi][ni] = zero4; }

  auto stage = [&](int t) {
    int k0 = t * 64;
    gload_lds16(aS1 + k0, &lA[w * 512]);
    gload_lds16(aS2 + k0, &lA[4096 + w * 512]);
    gload_lds16(b0S + k0, &lB0[w * 512]);
    gload_lds16(b1S + k0, &lB1[w * 512]);
  };

  const int NT = E_DIM / 64;
  for (int t = 0; t < NT; ++t) {
    if (t) __syncthreads();
    stage(t);
    __syncthreads();
    __builtin_amdgcn_s_setprio(1);
#pragma unroll
    for (int ks = 0; ks < 2; ++ks) {
      short8 a[2], b0[2], b1[2];
#pragma unroll
      for (int mi = 0; mi < 2; ++mi) {
        int r = wm * 32 + mi * 16 + frow;
        a[mi] = *(const short8*)&lA[r * 64 + ((ks * 4 + fk) ^ (r & 7)) * 8];
      }
#pragma unroll
      for (int ni = 0; ni < 2; ++ni) {
        int n = wn * 32 + ni * 16 + frow;
        int off = n * 64 + ((ks * 4 + fk) ^ (n & 7)) * 8;
        b0[ni] = *(const short8*)&lB0[off];
        b1[ni] = *(const short8*)&lB1[off];
      }
#pragma unroll
      for (int mi = 0; mi < 2; ++mi)
#pragma unroll
        for (int ni = 0; ni < 2; ++ni) {
          acc0[mi][ni] = __builtin_amdgcn_mfma_f32_16x16x32_bf16(a[mi], b0[ni], acc0[mi][ni], 0, 0, 0);
          acc1[mi][ni] = __builtin_amdgcn_mfma_f32_16x16x32_bf16(a[mi], b1[ni], acc1[mi][ni], 0, 0, 0);
        }
    }
    __builtin_amdgcn_s_setprio(0);
  }

#pragma unroll
  for (int mi = 0; mi < 2; ++mi) {
#pragma unroll
    for (int j = 0; j < 4; ++j) {
      int r = wm * 32 + mi * 16 + fk * 4 + j;
      if (r < rowsv) {
        __hip_bfloat16* hr = h + (size_t)(slot0 + r) * F_DIM + f0 + wn * 32;
#pragma unroll
        for (int ni = 0; ni < 2; ++ni) {
          float v0 = acc0[mi][ni][j];
          float v1 = acc1[mi][ni][j];
          float s = (v0 / (1.f + __expf(-v0))) * v1;
          hr[ni * 16 + frow] = __float2bfloat16(s);
        }
      }
    }
  }
}

// ---------------- GEMM2: parts[slot] = p * (h @ wo); BM=128 BN=64 BK=64 ----------------
__global__ __launch_bounds__(512, 4) void gemm2_kernel(const __hip_bfloat16* __restrict__ h,
                                                       const __hip_bfloat16* __restrict__ wot,
                                                       const int* __restrict__ ctrl,
                                                       const float* __restrict__ slot_prob,
                                                       float* __restrict__ parts) {
  int lin = blockIdx.x;                         // 640 = 8 * 80
  int logical = (lin & 7) * 80 + (lin >> 3);
  int mt = logical % 40;
  int ey = logical / 40;                        // 0..15
  if (mt >= ctrl[24]) return;
  int e = ctrl[32 + mt];
  int slot0 = ctrl[96 + mt];
  int rowsv = ctrl[160 + mt];
  int e0 = ey * 64;

  __shared__ alignas(16) short lA[128 * 64];
  __shared__ alignas(16) short lB[64 * 64];

  int tid = threadIdx.x;
  int w = tid >> 6, l = tid & 63;
  int wm = w >> 1, wn = w & 1;
  int frow = l & 15, fk = l >> 4;

  int r1 = tid >> 3;
  int kc = ((tid & 7) ^ (r1 & 7)) * 8;
  const __hip_bfloat16* aS1 = h + (size_t)(slot0 + r1) * F_DIM + kc;
  const __hip_bfloat16* aS2 = aS1 + (size_t)64 * F_DIM;
  const __hip_bfloat16* bS = wot + ((size_t)e * E_DIM + e0 + r1) * F_DIM + kc;

  f32x4 zero4 = {0.f, 0.f, 0.f, 0.f};
  f32x4 acc[2][2];
#pragma unroll
  for (int mi = 0; mi < 2; mi++)
#pragma unroll
    for (int ni = 0; ni < 2; ni++) acc[mi][ni] = zero4;

  auto stage = [&](int t) {
    int k0 = t * 64;
    gload_lds16(aS1 + k0, &lA[w * 512]);
    gload_lds16(aS2 + k0, &lA[4096 + w * 512]);
    gload_lds16(bS + k0, &lB[w * 512]);
  };

  const int NT = F_DIM / 64;
  for (int t = 0; t < NT; ++t) {
    if (t) __syncthreads();
    stage(t);
    __syncthreads();
    __builtin_amdgcn_s_setprio(1);
#pragma unroll
    for (int ks = 0; ks < 2; ++ks) {
      short8 a[2], b[2];
#pragma unroll
      for (int mi = 0; mi < 2; ++mi) {
        int r = wm * 32 + mi * 16 + frow;
        a[mi] = *(const short8*)&lA[r * 64 + ((ks * 4 + fk) ^ (r & 7)) * 8];
      }
#pragma unroll
      for (int ni = 0; ni < 2; ++ni) {
        int n = wn * 32 + ni * 16 + frow;
        b[ni] = *(const short8*)&lB[n * 64 + ((ks * 4 + fk) ^ (n & 7)) * 8];
      }
#pragma unroll
      for (int mi = 0; mi < 2; ++mi)
#pragma unroll
        for (int ni = 0; ni < 2; ++ni)
          acc[mi][ni] = __builtin_amdgcn_mfma_f32_16x16x32_bf16(a[mi], b[ni], acc[mi][ni], 0, 0, 0);
    }
    __builtin_amdgcn_s_setprio(0);
  }

#pragma unroll
  for (int mi = 0; mi < 2; ++mi) {
#pragma unroll
    for (int j = 0; j < 4; ++j) {
      int r = wm * 32 + mi * 16 + fk * 4 + j;
      if (r < rowsv) {
        int slot = slot0 + r;
        float p = slot_prob[slot];
        float* pr = parts + (size_t)slot * E_DIM + e0 + wn * 32;
#pragma unroll
        for (int ni = 0; ni < 2; ++ni)
          pr[ni * 16 + frow] = p * acc[mi][ni][j];
      }
    }
  }
}

// ---------------- combine: out[t] = parts[s1] + parts[s2] ----------------
__global__ __launch_bounds__(256) void combine_kernel(const float* __restrict__ parts,
                                                      const int* __restrict__ inv,
                                                      float* __restrict__ out) {
  int g = blockIdx.x * 256 + threadIdx.x;   // T_TOK*128
  int row = g >> 7, c = (g & 127) * 8;
  int s1 = inv[row * 2], s2 = inv[row * 2 + 1];
  const float4* p1 = (const float4*)(parts + (size_t)s1 * E_DIM + c);
  const float4* p2 = (const float4*)(parts + (size_t)s2 * E_DIM + c);
  float4 a0 = p1[0], a1 = p1[1], b0 = p2[0], b1 = p2[1];
  float4 o0 = {a0.x + b0.x, a0.y + b0.y, a0.z + b0.z, a0.w + b0.w};
  float4 o1 = {a1.x + b1.x, a1.y + b1.y, a1.z + b1.z, a1.w + b1.w};
  float4* op = (float4*)(out + (size_t)row * E_DIM + c);
  op[0] = o0; op[1] = o1;
}

extern "C" void kernel_launch(void* const* d_in, const int* in_sizes, int n_in,
                              void* d_out, int out_size, void* d_ws, size_t ws_size,
                              hipStream_t stream) {
  const float* x  = (const float*)d_in[0];
  const float* gk = (const float*)d_in[1];
  const float* w0 = (const float*)d_in[2];
  const float* w1 = (const float*)d_in[3];
  const float* wo = (const float*)d_in[4];
  float* out = (float*)d_out;
  char* ws = (char*)d_ws;

  const size_t SLOTS = 2 * T_TOK + 128;
  const size_t OFF_XB   = 0;
  const size_t OFF_W0T  = OFF_XB  + (size_t)T_TOK * E_DIM * 2;
  const size_t OFF_W1T  = OFF_W0T + (size_t)N_EXP * E_DIM * F_DIM * 2;
  const size_t OFF_WOT  = OFF_W1T + (size_t)N_EXP * E_DIM * F_DIM * 2;
  const size_t OFF_H    = OFF_WOT + (size_t)N_EXP * F_DIM * E_DIM * 2;
  const size_t OFF_STOK = OFF_H   + SLOTS * F_DIM * 2;
  const size_t OFF_SPRB = OFF_STOK + SLOTS * 4;
  const size_t OFF_TKE  = OFF_SPRB + SLOTS * 4;
  const size_t OFF_TKP  = OFF_TKE + (size_t)2 * T_TOK * 4;
  const size_t OFF_INV  = OFF_TKP + (size_t)2 * T_TOK * 4;
  const size_t OFF_CTRL = OFF_INV + (size_t)2 * T_TOK * 4;
  const size_t NEED     = OFF_CTRL + 1024;
  if (ws_size < NEED) return;

  __hip_bfloat16* xb   = (__hip_bfloat16*)(ws + OFF_XB);
  __hip_bfloat16* w0t  = (__hip_bfloat16*)(ws + OFF_W0T);
  __hip_bfloat16* w1t  = (__hip_bfloat16*)(ws + OFF_W1T);
  __hip_bfloat16* wot  = (__hip_bfloat16*)(ws + OFF_WOT);
  __hip_bfloat16* hbuf = (__hip_bfloat16*)(ws + OFF_H);
  float* parts     = (float*)(ws + OFF_W0T);   // alias: w0t dead after gemm1
  int*   slot_tok  = (int*)(ws + OFF_STOK);
  float* slot_prob = (float*)(ws + OFF_SPRB);
  int*   tk_e      = (int*)(ws + OFF_TKE);
  float* tk_p      = (float*)(ws + OFF_TKP);
  int*   inv       = (int*)(ws + OFF_INV);
  int*   ctrl      = (int*)(ws + OFF_CTRL);

  hipMemsetAsync(ctrl, 0, 1024, stream);
  hipMemsetAsync(slot_tok + 2 * T_TOK, 0, 128 * 4, stream);

  prep_kernel<<<3072, 256, 0, stream>>>(w0, w1, x, gk, w0t, w1t, xb, tk_e, tk_p, ctrl);
  scanperm_kernel<<<1, 256, 0, stream>>>(tk_e, tk_p, ctrl, slot_tok, slot_prob, inv);
  gemm1_kernel<<<3328, 512, 0, stream>>>(xb, w0t, w1t, ctrl, slot_tok, hbuf, wo, wot);
  gemm2_kernel<<<640, 512, 0, stream>>>(hbuf, wot, ctrl, slot_prob, parts);
  combine_kernel<<<(T_TOK * 128) / 256, 256, 0, stream>>>(parts, inv, out);
}

// Round 15
// 195.568 us; speedup vs baseline: 1.0551x; 1.0551x over previous
//
#include <hip/hip_runtime.h>
#include <hip/hip_bf16.h>

#define T_TOK 2048
#define E_DIM 1024
#define F_DIM 2048
#define N_EXP 8

typedef __attribute__((ext_vector_type(8))) short short8;
typedef __attribute__((ext_vector_type(4))) float f32x4;

__device__ __forceinline__ short bf2s(__hip_bfloat16 v) {
  union { __hip_bfloat16 b; short s; } u; u.b = v; return u.s;
}

__device__ __forceinline__ void gload_lds16(const void* g, void* l) {
  __builtin_amdgcn_global_load_lds((const __attribute__((address_space(1))) void*)g,
                                   (__attribute__((address_space(3))) void*)l, 16, 0, 0);
}

// ---- 64x64 transpose tile, stride-64 XOR layout:
// off(r,c) = r*64 + (c ^ 4*((r>>3)&7))   [fp32 elements]
// writes: 4x aligned ds_write_b128 at the 8-words/bank floor (optimal);
// reads: 16 scalar ds_read_b32, exactly 2-way banks (free per m136).
// global patterns identical to the proven r4 body.
__device__ __forceinline__ void transpose_tile_swz(const float* __restrict__ src,
                                                   __hip_bfloat16* __restrict__ dst,
                                                   int C, int R, int r0, int c0,
                                                   int tt, float* lt) {
#pragma unroll
  for (int i = 0; i < 4; i++) {
    int chunk = i * 256 + tt;
    int r = chunk >> 4, c4 = (chunk & 15) * 4;
    float4 v = *(const float4*)(src + (size_t)(r0 + r) * C + c0 + c4);
    *(float4*)&lt[r * 64 + (c4 ^ (4 * ((r >> 3) & 7)))] = v;
  }
  __syncthreads();
#pragma unroll
  for (int i = 0; i < 2; i++) {
    int chunk = i * 256 + tt;
    int c = chunk >> 3, rr = (chunk & 7) * 8;
    short8 o;
#pragma unroll
    for (int j = 0; j < 8; j++) {
      int r = rr + j;
      o[j] = bf2s(__float2bfloat16(lt[r * 64 + (c ^ (4 * ((r >> 3) & 7)))]));
    }
    *(short8*)(dst + (size_t)(c0 + c) * R + r0 + rr) = o;
  }
}

// ---------------- prep3d: router (z=0) + convert_x (z=1) first, then w01 transpose (z=2..17) ----------------
__global__ __launch_bounds__(256) void prep3d_kernel(const float* __restrict__ w0,
                                                     const float* __restrict__ w1,
                                                     const float* __restrict__ x,
                                                     const float* __restrict__ gk,
                                                     __hip_bfloat16* __restrict__ w0t,
                                                     __hip_bfloat16* __restrict__ w1t,
                                                     __hip_bfloat16* __restrict__ xb,
                                                     int* __restrict__ tk_e,
                                                     float* __restrict__ tk_p,
                                                     int* __restrict__ counts) {
  __shared__ float lt[64 * 64];
  int z = blockIdx.z;
  int tid = threadIdx.x;
  if (z >= 2) {
    int zz = z - 2;
    int e = zz & 7;
    const float* src = (zz < 8 ? w0 : w1) + (size_t)e * E_DIM * F_DIM;
    __hip_bfloat16* dst = (zz < 8 ? w0t : w1t) + (size_t)e * E_DIM * F_DIM;
    transpose_tile_swz(src, dst, F_DIM, E_DIM, blockIdx.y * 64, blockIdx.x * 64, tid, lt);
    return;
  }
  int idx = blockIdx.y * 32 + blockIdx.x;   // 0..511
  if (z == 1) {
#pragma unroll
    for (int pass = 0; pass < 2; ++pass) {
      size_t i = (size_t)idx * 4096 + pass * 2048 + tid * 8;
      float4 a = *(const float4*)(x + i);
      float4 b = *(const float4*)(x + i + 4);
      short8 oo;
      oo[0] = bf2s(__float2bfloat16(a.x)); oo[1] = bf2s(__float2bfloat16(a.y));
      oo[2] = bf2s(__float2bfloat16(a.z)); oo[3] = bf2s(__float2bfloat16(a.w));
      oo[4] = bf2s(__float2bfloat16(b.x)); oo[5] = bf2s(__float2bfloat16(b.y));
      oo[6] = bf2s(__float2bfloat16(b.z)); oo[7] = bf2s(__float2bfloat16(b.w));
      *(short8*)(xb + i) = oo;
    }
    return;
  }
  // z == 0: router, fp64 logits, top-2, softmax
  int w = tid >> 6, l = tid & 63;
  int t = idx * 4 + w;
  const float* xr = x + (size_t)t * E_DIM;
  double acc[N_EXP];
#pragma unroll
  for (int n = 0; n < N_EXP; n++) acc[n] = 0.0;
  for (int j = 0; j < 16; j++) {
    int i = j * 64 + l;
    double xv = (double)xr[i];
    const float* g = gk + (size_t)i * N_EXP;
#pragma unroll
    for (int n = 0; n < N_EXP; n++) acc[n] += xv * (double)g[n];
  }
#pragma unroll
  for (int off = 32; off > 0; off >>= 1) {
#pragma unroll
    for (int n = 0; n < N_EXP; n++) acc[n] += __shfl_down(acc[n], off);
  }
  if (l == 0) {
    int e1 = 0; double v1 = acc[0];
    for (int n = 1; n < N_EXP; n++) if (acc[n] > v1) { v1 = acc[n]; e1 = n; }
    int e2 = -1; double v2 = -1e300;
    for (int n = 0; n < N_EXP; n++) if (n != e1 && acc[n] > v2) { v2 = acc[n]; e2 = n; }
    float ex = __expf((float)(v2 - v1));     // <= 1
    float p1 = 1.f / (1.f + ex);
    float p2 = ex / (1.f + ex);
    tk_e[t * 2 + 0] = e1; tk_p[t * 2 + 0] = p1;
    tk_e[t * 2 + 1] = e2; tk_p[t * 2 + 1] = p2;
    atomicAdd(&counts[e1], 1);
    atomicAdd(&counts[e2], 1);
  }
}

// ---------------- scan + permute, single block ----------------
__global__ __launch_bounds__(256) void scanperm_kernel(const int* __restrict__ tk_e,
                                                       const float* __restrict__ tk_p,
                                                       int* __restrict__ ctrl,
                                                       int* __restrict__ slot_tok,
                                                       float* __restrict__ slot_prob,
                                                       int* __restrict__ inv) {
  __shared__ int offs[8], cur[8];
  int tid = threadIdx.x;
  if (tid == 0) {
    int off = 0, idx = 0;
    for (int e = 0; e < N_EXP; e++) {
      offs[e] = off; cur[e] = 0;
      int c = ctrl[e];
      for (int m0 = 0; m0 < c; m0 += 128) {
        ctrl[32 + idx] = e;
        ctrl[96 + idx] = off + m0;
        ctrl[160 + idx] = (c - m0 < 128) ? (c - m0) : 128;
        idx++;
      }
      off += c;
    }
    ctrl[24] = idx;
  }
  __syncthreads();
  for (int g = tid; g < 2 * T_TOK; g += 256) {
    int e = tk_e[g];
    float p = tk_p[g];
    int pos = atomicAdd(&cur[e], 1);
    int slot = offs[e] + pos;
    slot_tok[slot] = g >> 1;
    slot_prob[slot] = p;
    inv[g] = slot;
  }
}

// ---------------- GEMM1 (+embedded wo transpose): h = silu(X@w0)*(X@w1) ----------------
// gemm: blocks [0,1280): BM=128 BN=64 BK=64, 8 waves (4m x 2n), 32KB LDS, 4 blk/CU
// transpose: blocks [1280,3328): wo [F][E]fp32 -> wot [E][F]bf16, 2x 64x64 tiles/block
__global__ __launch_bounds__(512, 4) void gemm1_kernel(const __hip_bfloat16* __restrict__ xb,
                                                       const __hip_bfloat16* __restrict__ w0t,
                                                       const __hip_bfloat16* __restrict__ w1t,
                                                       const int* __restrict__ ctrl,
                                                       const int* __restrict__ slot_tok,
                                                       __hip_bfloat16* __restrict__ h,
                                                       const float* __restrict__ wo,
                                                       __hip_bfloat16* __restrict__ wot) {
  __shared__ float ltf[2][64 * 64];            // 32 KB union
  short* lA  = (short*)&ltf[0][0];             // 8192 shorts (16 KB)
  short* lB0 = lA + 8192;                      // 4096 shorts (8 KB)
  short* lB1 = lA + 12288;                     // 4096 shorts (8 KB)

  if (blockIdx.x >= 1280) {
    int half = threadIdx.x >> 8, tt = threadIdx.x & 255;
    int tile = (blockIdx.x - 1280) * 2 + half;    // 0..4095
    int e = tile >> 9;
    int t2 = tile & 511;
    int r0 = (t2 & 31) * 64;        // F tiles
    int c0 = (t2 >> 5) * 64;        // E tiles
    transpose_tile_swz(wo + (size_t)e * F_DIM * E_DIM, wot + (size_t)e * E_DIM * F_DIM,
                       E_DIM, F_DIM, r0, c0, tt, &ltf[half][0]);
    return;
  }

  int lin = blockIdx.x;                         // 1280 = 8 * 160
  int logical = (lin & 7) * 160 + (lin >> 3);   // XCD-chunked
  int mt = logical % 40;
  int fy = logical / 40;                        // 0..31
  if (mt >= ctrl[24]) return;
  int e = ctrl[32 + mt];
  int slot0 = ctrl[96 + mt];
  int rowsv = ctrl[160 + mt];
  int f0 = fy * 64;

  int tid = threadIdx.x;
  int w = tid >> 6, l = tid & 63;
  int wm = w >> 1, wn = w & 1;
  int frow = l & 15, fk = l >> 4;

  int r1 = tid >> 3;
  int kc = ((tid & 7) ^ (r1 & 7)) * 8;
  int tokA1 = slot_tok[slot0 + r1];
  int tokA2 = slot_tok[slot0 + r1 + 64];
  const __hip_bfloat16* aS1 = xb + (size_t)tokA1 * E_DIM + kc;
  const __hip_bfloat16* aS2 = xb + (size_t)tokA2 * E_DIM + kc;
  const __hip_bfloat16* b0S = w0t + ((size_t)e * F_DIM + f0 + r1) * E_DIM + kc;
  const __hip_bfloat16* b1S = w1t + ((size_t)e * F_DIM + f0 + r1) * E_DIM + kc;

  f32x4 zero4 = {0.f, 0.f, 0.f, 0.f};
  f32x4 acc0[2][2], acc1[2][2];
#pragma unroll
  for (int mi = 0; mi < 2; mi++)
#pragma unroll
    for (int ni = 0; ni < 2; ni++) { acc0[mi][ni] = zero4; acc1[mi][ni] = zero4; }

  auto stage = [&](int t) {
    int k0 = t * 64;
    gload_lds16(aS1 + k0, &lA[w * 512]);
    gload_lds16(aS2 + k0, &lA[4096 + w * 512]);
    gload_lds16(b0S + k0, &lB0[w * 512]);
    gload_lds16(b1S + k0, &lB1[w * 512]);
  };

  const int NT = E_DIM / 64;
  for (int t = 0; t < NT; ++t) {
    if (t) __syncthreads();
    stage(t);
    __syncthreads();
    __builtin_amdgcn_s_setprio(1);
#pragma unroll
    for (int ks = 0; ks < 2; ++ks) {
      short8 a[2], b0[2], b1[2];
#pragma unroll
      for (int mi = 0; mi < 2; ++mi) {
        int r = wm * 32 + mi * 16 + frow;
        a[mi] = *(const short8*)&lA[r * 64 + ((ks * 4 + fk) ^ (r & 7)) * 8];
      }
#pragma unroll
      for (int ni = 0; ni < 2; ++ni) {
        int n = wn * 32 + ni * 16 + frow;
        int off = n * 64 + ((ks * 4 + fk) ^ (n & 7)) * 8;
        b0[ni] = *(const short8*)&lB0[off];
        b1[ni] = *(const short8*)&lB1[off];
      }
#pragma unroll
      for (int mi = 0; mi < 2; ++mi)
#pragma unroll
        for (int ni = 0; ni < 2; ++ni) {
          acc0[mi][ni] = __builtin_amdgcn_mfma_f32_16x16x32_bf16(a[mi], b0[ni], acc0[mi][ni], 0, 0, 0);
          acc1[mi][ni] = __builtin_amdgcn_mfma_f32_16x16x32_bf16(a[mi], b1[ni], acc1[mi][ni], 0, 0, 0);
        }
    }
    __builtin_amdgcn_s_setprio(0);
  }

#pragma unroll
  for (int mi = 0; mi < 2; ++mi) {
#pragma unroll
    for (int j = 0; j < 4; ++j) {
      int r = wm * 32 + mi * 16 + fk * 4 + j;
      if (r < rowsv) {
        __hip_bfloat16* hr = h + (size_t)(slot0 + r) * F_DIM + f0 + wn * 32;
#pragma unroll
        for (int ni = 0; ni < 2; ++ni) {
          float v0 = acc0[mi][ni][j];
          float v1 = acc1[mi][ni][j];
          float s = (v0 / (1.f + __expf(-v0))) * v1;
          hr[ni * 16 + frow] = __float2bfloat16(s);
        }
      }
    }
  }
}

// ---------------- GEMM2: parts[slot] = p * (h @ wo) in bf16; BM=128 BN=64 BK=64 ----------------
__global__ __launch_bounds__(512, 4) void gemm2_kernel(const __hip_bfloat16* __restrict__ h,
                                                       const __hip_bfloat16* __restrict__ wot,
                                                       const int* __restrict__ ctrl,
                                                       const float* __restrict__ slot_prob,
                                                       __hip_bfloat16* __restrict__ parts) {
  int lin = blockIdx.x;                         // 640 = 8 * 80
  int logical = (lin & 7) * 80 + (lin >> 3);
  int mt = logical % 40;
  int ey = logical / 40;                        // 0..15
  if (mt >= ctrl[24]) return;
  int e = ctrl[32 + mt];
  int slot0 = ctrl[96 + mt];
  int rowsv = ctrl[160 + mt];
  int e0 = ey * 64;

  __shared__ alignas(16) short lA[128 * 64];
  __shared__ alignas(16) short lB[64 * 64];

  int tid = threadIdx.x;
  int w = tid >> 6, l = tid & 63;
  int wm = w >> 1, wn = w & 1;
  int frow = l & 15, fk = l >> 4;

  int r1 = tid >> 3;
  int kc = ((tid & 7) ^ (r1 & 7)) * 8;
  const __hip_bfloat16* aS1 = h + (size_t)(slot0 + r1) * F_DIM + kc;
  const __hip_bfloat16* aS2 = aS1 + (size_t)64 * F_DIM;
  const __hip_bfloat16* bS = wot + ((size_t)e * E_DIM + e0 + r1) * F_DIM + kc;

  f32x4 zero4 = {0.f, 0.f, 0.f, 0.f};
  f32x4 acc[2][2];
#pragma unroll
  for (int mi = 0; mi < 2; mi++)
#pragma unroll
    for (int ni = 0; ni < 2; ni++) acc[mi][ni] = zero4;

  auto stage = [&](int t) {
    int k0 = t * 64;
    gload_lds16(aS1 + k0, &lA[w * 512]);
    gload_lds16(aS2 + k0, &lA[4096 + w * 512]);
    gload_lds16(bS + k0, &lB[w * 512]);
  };

  const int NT = F_DIM / 64;
  for (int t = 0; t < NT; ++t) {
    if (t) __syncthreads();
    stage(t);
    __syncthreads();
    __builtin_amdgcn_s_setprio(1);
#pragma unroll
    for (int ks = 0; ks < 2; ++ks) {
      short8 a[2], b[2];
#pragma unroll
      for (int mi = 0; mi < 2; ++mi) {
        int r = wm * 32 + mi * 16 + frow;
        a[mi] = *(const short8*)&lA[r * 64 + ((ks * 4 + fk) ^ (r & 7)) * 8];
      }
#pragma unroll
      for (int ni = 0; ni < 2; ++ni) {
        int n = wn * 32 + ni * 16 + frow;
        b[ni] = *(const short8*)&lB[n * 64 + ((ks * 4 + fk) ^ (n & 7)) * 8];
      }
#pragma unroll
      for (int mi = 0; mi < 2; ++mi)
#pragma unroll
        for (int ni = 0; ni < 2; ++ni)
          acc[mi][ni] = __builtin_amdgcn_mfma_f32_16x16x32_bf16(a[mi], b[ni], acc[mi][ni], 0, 0, 0);
    }
    __builtin_amdgcn_s_setprio(0);
  }

#pragma unroll
  for (int mi = 0; mi < 2; ++mi) {
#pragma unroll
    for (int j = 0; j < 4; ++j) {
      int r = wm * 32 + mi * 16 + fk * 4 + j;
      if (r < rowsv) {
        int slot = slot0 + r;
        float p = slot_prob[slot];
        __hip_bfloat16* pr = parts + (size_t)slot * E_DIM + e0 + wn * 32;
#pragma unroll
        for (int ni = 0; ni < 2; ++ni)
          pr[ni * 16 + frow] = __float2bfloat16(p * acc[mi][ni][j]);
      }
    }
  }
}

// ---------------- combine: out[t] = parts[s1] + parts[s2] (bf16 parts -> fp32 out) ----------------
__global__ __launch_bounds__(256) void combine_kernel(const __hip_bfloat16* __restrict__ parts,
                                                      const int* __restrict__ inv,
                                                      float* __restrict__ out) {
  int g = blockIdx.x * 256 + threadIdx.x;   // T_TOK*128
  int row = g >> 7, c = (g & 127) * 8;
  int s1 = inv[row * 2], s2 = inv[row * 2 + 1];
  short8 p1 = *(const short8*)(parts + (size_t)s1 * E_DIM + c);
  short8 p2 = *(const short8*)(parts + (size_t)s2 * E_DIM + c);
  float o[8];
#pragma unroll
  for (int j = 0; j < 8; ++j) {
    union { short s; __hip_bfloat16 b; } u1, u2;
    u1.s = p1[j]; u2.s = p2[j];
    o[j] = __bfloat162float(u1.b) + __bfloat162float(u2.b);
  }
  float4* op = (float4*)(out + (size_t)row * E_DIM + c);
  op[0] = make_float4(o[0], o[1], o[2], o[3]);
  op[1] = make_float4(o[4], o[5], o[6], o[7]);
}

extern "C" void kernel_launch(void* const* d_in, const int* in_sizes, int n_in,
                              void* d_out, int out_size, void* d_ws, size_t ws_size,
                              hipStream_t stream) {
  const float* x  = (const float*)d_in[0];
  const float* gk = (const float*)d_in[1];
  const float* w0 = (const float*)d_in[2];
  const float* w1 = (const float*)d_in[3];
  const float* wo = (const float*)d_in[4];
  float* out = (float*)d_out;
  char* ws = (char*)d_ws;

  const size_t SLOTS = 2 * T_TOK + 128;
  const size_t OFF_XB   = 0;
  const size_t OFF_W0T  = OFF_XB  + (size_t)T_TOK * E_DIM * 2;
  const size_t OFF_W1T  = OFF_W0T + (size_t)N_EXP * E_DIM * F_DIM * 2;
  const size_t OFF_WOT  = OFF_W1T + (size_t)N_EXP * E_DIM * F_DIM * 2;
  const size_t OFF_H    = OFF_WOT + (size_t)N_EXP * F_DIM * E_DIM * 2;
  const size_t OFF_STOK = OFF_H   + SLOTS * F_DIM * 2;
  const size_t OFF_SPRB = OFF_STOK + SLOTS * 4;
  const size_t OFF_TKE  = OFF_SPRB + SLOTS * 4;
  const size_t OFF_TKP  = OFF_TKE + (size_t)2 * T_TOK * 4;
  const size_t OFF_INV  = OFF_TKP + (size_t)2 * T_TOK * 4;
  const size_t OFF_CTRL = OFF_INV + (size_t)2 * T_TOK * 4;
  const size_t NEED     = OFF_CTRL + 1024;
  if (ws_size < NEED) return;

  __hip_bfloat16* xb   = (__hip_bfloat16*)(ws + OFF_XB);
  __hip_bfloat16* w0t  = (__hip_bfloat16*)(ws + OFF_W0T);
  __hip_bfloat16* w1t  = (__hip_bfloat16*)(ws + OFF_W1T);
  __hip_bfloat16* wot  = (__hip_bfloat16*)(ws + OFF_WOT);
  __hip_bfloat16* hbuf = (__hip_bfloat16*)(ws + OFF_H);
  __hip_bfloat16* parts = (__hip_bfloat16*)(ws + OFF_W0T);  // alias: w0t dead after gemm1
  int*   slot_tok  = (int*)(ws + OFF_STOK);
  float* slot_prob = (float*)(ws + OFF_SPRB);
  int*   tk_e      = (int*)(ws + OFF_TKE);
  float* tk_p      = (float*)(ws + OFF_TKP);
  int*   inv       = (int*)(ws + OFF_INV);
  int*   ctrl      = (int*)(ws + OFF_CTRL);

  hipMemsetAsync(ctrl, 0, 1024, stream);
  hipMemsetAsync(slot_tok + 2 * T_TOK, 0, 128 * 4, stream);

  prep3d_kernel<<<dim3(32, 16, 18), 256, 0, stream>>>(w0, w1, x, gk, w0t, w1t, xb, tk_e, tk_p, ctrl);
  scanperm_kernel<<<1, 256, 0, stream>>>(tk_e, tk_p, ctrl, slot_tok, slot_prob, inv);
  gemm1_kernel<<<3328, 512, 0, stream>>>(xb, w0t, w1t, ctrl, slot_tok, hbuf, wo, wot);
  gemm2_kernel<<<640, 512, 0, stream>>>(hbuf, wot, ctrl, slot_prob, parts);
  combine_kernel<<<(T_TOK * 128) / 256, 256, 0, stream>>>(parts, inv, out);
}

// Round 16
// 194.620 us; speedup vs baseline: 1.0603x; 1.0049x over previous
//
#include <hip/hip_runtime.h>
#include <hip/hip_bf16.h>

#define T_TOK 2048
#define E_DIM 1024
#define F_DIM 2048
#define N_EXP 8

typedef __attribute__((ext_vector_type(8))) short short8;
typedef __attribute__((ext_vector_type(4))) float f32x4;

__device__ __forceinline__ short bf2s(__hip_bfloat16 v) {
  union { __hip_bfloat16 b; short s; } u; u.b = v; return u.s;
}

__device__ __forceinline__ void gload_lds16(const void* g, void* l) {
  __builtin_amdgcn_global_load_lds((const __attribute__((address_space(1))) void*)g,
                                   (__attribute__((address_space(3))) void*)l, 16, 0, 0);
}

// ---- 64x64 transpose tile -> BLOCKED (panel) output: dst[kt][c][64] with kt=r0/64.
// A wave's stores cover 1KB fully contiguous (streaming writes, like convert_x).
// LDS: stride-64 XOR layout (b128 writes at bank floor; scalar reads 2-way free).
__device__ __forceinline__ void transpose_tile_blk(const float* __restrict__ src,
                                                   __hip_bfloat16* __restrict__ dst,
                                                   int C, int r0, int c0,
                                                   int tt, float* lt) {
#pragma unroll
  for (int i = 0; i < 4; i++) {
    int chunk = i * 256 + tt;
    int r = chunk >> 4, c4 = (chunk & 15) * 4;
    float4 v = *(const float4*)(src + (size_t)(r0 + r) * C + c0 + c4);
    *(float4*)&lt[r * 64 + (c4 ^ (4 * ((r >> 3) & 7)))] = v;
  }
  __syncthreads();
  __hip_bfloat16* pbase = dst + (size_t)(r0 >> 6) * ((size_t)C * 64);
#pragma unroll
  for (int i = 0; i < 2; i++) {
    int chunk = i * 256 + tt;
    int c = chunk >> 3, rr = (chunk & 7) * 8;
    short8 o;
#pragma unroll
    for (int j = 0; j < 8; j++) {
      int r = rr + j;
      o[j] = bf2s(__float2bfloat16(lt[r * 64 + (c ^ (4 * ((r >> 3) & 7)))]));
    }
    *(short8*)(pbase + (size_t)(c0 + c) * 64 + rr) = o;
  }
}

// ---------------- prep3d: router (z=0) + convert_x (z=1) first, then w01 transpose (z=2..17) ----------------
__global__ __launch_bounds__(256) void prep3d_kernel(const float* __restrict__ w0,
                                                     const float* __restrict__ w1,
                                                     const float* __restrict__ x,
                                                     const float* __restrict__ gk,
                                                     __hip_bfloat16* __restrict__ w0t,
                                                     __hip_bfloat16* __restrict__ w1t,
                                                     __hip_bfloat16* __restrict__ xb,
                                                     int* __restrict__ tk_e,
                                                     float* __restrict__ tk_p,
                                                     int* __restrict__ counts) {
  __shared__ float lt[64 * 64];
  int z = blockIdx.z;
  int tid = threadIdx.x;
  if (z >= 2) {
    int zz = z - 2;
    int e = zz & 7;
    const float* src = (zz < 8 ? w0 : w1) + (size_t)e * E_DIM * F_DIM;
    __hip_bfloat16* dst = (zz < 8 ? w0t : w1t) + (size_t)e * E_DIM * F_DIM;
    transpose_tile_blk(src, dst, F_DIM, blockIdx.y * 64, blockIdx.x * 64, tid, lt);
    return;
  }
  int idx = blockIdx.y * 32 + blockIdx.x;   // 0..511
  if (z == 1) {
#pragma unroll
    for (int pass = 0; pass < 2; ++pass) {
      size_t i = (size_t)idx * 4096 + pass * 2048 + tid * 8;
      float4 a = *(const float4*)(x + i);
      float4 b = *(const float4*)(x + i + 4);
      short8 oo;
      oo[0] = bf2s(__float2bfloat16(a.x)); oo[1] = bf2s(__float2bfloat16(a.y));
      oo[2] = bf2s(__float2bfloat16(a.z)); oo[3] = bf2s(__float2bfloat16(a.w));
      oo[4] = bf2s(__float2bfloat16(b.x)); oo[5] = bf2s(__float2bfloat16(b.y));
      oo[6] = bf2s(__float2bfloat16(b.z)); oo[7] = bf2s(__float2bfloat16(b.w));
      *(short8*)(xb + i) = oo;
    }
    return;
  }
  // z == 0: router, fp64 logits, top-2, softmax
  int w = tid >> 6, l = tid & 63;
  int t = idx * 4 + w;
  const float* xr = x + (size_t)t * E_DIM;
  double acc[N_EXP];
#pragma unroll
  for (int n = 0; n < N_EXP; n++) acc[n] = 0.0;
  for (int j = 0; j < 16; j++) {
    int i = j * 64 + l;
    double xv = (double)xr[i];
    const float* g = gk + (size_t)i * N_EXP;
#pragma unroll
    for (int n = 0; n < N_EXP; n++) acc[n] += xv * (double)g[n];
  }
#pragma unroll
  for (int off = 32; off > 0; off >>= 1) {
#pragma unroll
    for (int n = 0; n < N_EXP; n++) acc[n] += __shfl_down(acc[n], off);
  }
  if (l == 0) {
    int e1 = 0; double v1 = acc[0];
    for (int n = 1; n < N_EXP; n++) if (acc[n] > v1) { v1 = acc[n]; e1 = n; }
    int e2 = -1; double v2 = -1e300;
    for (int n = 0; n < N_EXP; n++) if (n != e1 && acc[n] > v2) { v2 = acc[n]; e2 = n; }
    float ex = __expf((float)(v2 - v1));     // <= 1
    float p1 = 1.f / (1.f + ex);
    float p2 = ex / (1.f + ex);
    tk_e[t * 2 + 0] = e1; tk_p[t * 2 + 0] = p1;
    tk_e[t * 2 + 1] = e2; tk_p[t * 2 + 1] = p2;
    atomicAdd(&counts[e1], 1);
    atomicAdd(&counts[e2], 1);
  }
}

// ---------------- scan + permute, single block ----------------
__global__ __launch_bounds__(256) void scanperm_kernel(const int* __restrict__ tk_e,
                                                       const float* __restrict__ tk_p,
                                                       int* __restrict__ ctrl,
                                                       int* __restrict__ slot_tok,
                                                       float* __restrict__ slot_prob,
                                                       int* __restrict__ inv) {
  __shared__ int offs[8], cur[8];
  int tid = threadIdx.x;
  if (tid == 0) {
    int off = 0, idx = 0;
    for (int e = 0; e < N_EXP; e++) {
      offs[e] = off; cur[e] = 0;
      int c = ctrl[e];
      for (int m0 = 0; m0 < c; m0 += 128) {
        ctrl[32 + idx] = e;
        ctrl[96 + idx] = off + m0;
        ctrl[160 + idx] = (c - m0 < 128) ? (c - m0) : 128;
        idx++;
      }
      off += c;
    }
    ctrl[24] = idx;
  }
  __syncthreads();
  for (int g = tid; g < 2 * T_TOK; g += 256) {
    int e = tk_e[g];
    float p = tk_p[g];
    int pos = atomicAdd(&cur[e], 1);
    int slot = offs[e] + pos;
    slot_tok[slot] = g >> 1;
    slot_prob[slot] = p;
    inv[g] = slot;
  }
}

// ---------------- GEMM1 (+embedded wo transpose): h = silu(X@w0)*(X@w1) ----------------
// gemm: blocks [0,1280): BM=128 BN=64 BK=64, 8 waves (4m x 2n), 32KB LDS, 4 blk/CU
// B layout: blocked panels wNt[e][kt][f][64]
// transpose: blocks [1280,3328): wo fp32 [F][E] -> wot panels [ft][e2][64]
__global__ __launch_bounds__(512, 4) void gemm1_kernel(const __hip_bfloat16* __restrict__ xb,
                                                       const __hip_bfloat16* __restrict__ w0t,
                                                       const __hip_bfloat16* __restrict__ w1t,
                                                       const int* __restrict__ ctrl,
                                                       const int* __restrict__ slot_tok,
                                                       __hip_bfloat16* __restrict__ h,
                                                       const float* __restrict__ wo,
                                                       __hip_bfloat16* __restrict__ wot) {
  __shared__ float ltf[2][64 * 64];            // 32 KB union
  short* lA  = (short*)&ltf[0][0];             // 8192 shorts (16 KB)
  short* lB0 = lA + 8192;                      // 4096 shorts (8 KB)
  short* lB1 = lA + 12288;                     // 4096 shorts (8 KB)

  if (blockIdx.x >= 1280) {
    int half = threadIdx.x >> 8, tt = threadIdx.x & 255;
    int tile = (blockIdx.x - 1280) * 2 + half;    // 0..4095
    int e = tile >> 9;
    int t2 = tile & 511;
    int r0 = (t2 & 31) * 64;        // F tiles
    int c0 = (t2 >> 5) * 64;        // E tiles
    transpose_tile_blk(wo + (size_t)e * F_DIM * E_DIM, wot + (size_t)e * E_DIM * F_DIM,
                       E_DIM, r0, c0, tt, &ltf[half][0]);
    return;
  }

  int lin = blockIdx.x;                         // 1280 = 8 * 160
  int logical = (lin & 7) * 160 + (lin >> 3);   // XCD-chunked
  int mt = logical % 40;
  int fy = logical / 40;                        // 0..31
  if (mt >= ctrl[24]) return;
  int e = ctrl[32 + mt];
  int slot0 = ctrl[96 + mt];
  int rowsv = ctrl[160 + mt];
  int f0 = fy * 64;

  int tid = threadIdx.x;
  int w = tid >> 6, l = tid & 63;
  int wm = w >> 1, wn = w & 1;
  int frow = l & 15, fk = l >> 4;

  int r1 = tid >> 3;
  int kc = ((tid & 7) ^ (r1 & 7)) * 8;
  int tokA1 = slot_tok[slot0 + r1];
  int tokA2 = slot_tok[slot0 + r1 + 64];
  const __hip_bfloat16* aS1 = xb + (size_t)tokA1 * E_DIM + kc;
  const __hip_bfloat16* aS2 = xb + (size_t)tokA2 * E_DIM + kc;
  // blocked-panel B: base = e*F*E + (f0+r1)*64 + kc; K-step stride = F*64
  const __hip_bfloat16* b0S = w0t + (size_t)e * F_DIM * E_DIM + (f0 + r1) * 64 + kc;
  const __hip_bfloat16* b1S = w1t + (size_t)e * F_DIM * E_DIM + (f0 + r1) * 64 + kc;

  f32x4 zero4 = {0.f, 0.f, 0.f, 0.f};
  f32x4 acc0[2][2], acc1[2][2];
#pragma unroll
  for (int mi = 0; mi < 2; mi++)
#pragma unroll
    for (int ni = 0; ni < 2; ni++) { acc0[mi][ni] = zero4; acc1[mi][ni] = zero4; }

  auto stage = [&](int t) {
    int k0 = t * 64;
    size_t bk = (size_t)t * (F_DIM * 64);
    gload_lds16(aS1 + k0, &lA[w * 512]);
    gload_lds16(aS2 + k0, &lA[4096 + w * 512]);
    gload_lds16(b0S + bk, &lB0[w * 512]);
    gload_lds16(b1S + bk, &lB1[w * 512]);
  };

  const int NT = E_DIM / 64;
  for (int t = 0; t < NT; ++t) {
    if (t) __syncthreads();
    stage(t);
    __syncthreads();
    __builtin_amdgcn_s_setprio(1);
#pragma unroll
    for (int ks = 0; ks < 2; ++ks) {
      short8 a[2], b0[2], b1[2];
#pragma unroll
      for (int mi = 0; mi < 2; ++mi) {
        int r = wm * 32 + mi * 16 + frow;
        a[mi] = *(const short8*)&lA[r * 64 + ((ks * 4 + fk) ^ (r & 7)) * 8];
      }
#pragma unroll
      for (int ni = 0; ni < 2; ++ni) {
        int n = wn * 32 + ni * 16 + frow;
        int off = n * 64 + ((ks * 4 + fk) ^ (n & 7)) * 8;
        b0[ni] = *(const short8*)&lB0[off];
        b1[ni] = *(const short8*)&lB1[off];
      }
#pragma unroll
      for (int mi = 0; mi < 2; ++mi)
#pragma unroll
        for (int ni = 0; ni < 2; ++ni) {
          acc0[mi][ni] = __builtin_amdgcn_mfma_f32_16x16x32_bf16(a[mi], b0[ni], acc0[mi][ni], 0, 0, 0);
          acc1[mi][ni] = __builtin_amdgcn_mfma_f32_16x16x32_bf16(a[mi], b1[ni], acc1[mi][ni], 0, 0, 0);
        }
    }
    __builtin_amdgcn_s_setprio(0);
  }

#pragma unroll
  for (int mi = 0; mi < 2; ++mi) {
#pragma unroll
    for (int j = 0; j < 4; ++j) {
      int r = wm * 32 + mi * 16 + fk * 4 + j;
      if (r < rowsv) {
        __hip_bfloat16* hr = h + (size_t)(slot0 + r) * F_DIM + f0 + wn * 32;
#pragma unroll
        for (int ni = 0; ni < 2; ++ni) {
          float v0 = acc0[mi][ni][j];
          float v1 = acc1[mi][ni][j];
          float s = (v0 / (1.f + __expf(-v0))) * v1;
          hr[ni * 16 + frow] = __float2bfloat16(s);
        }
      }
    }
  }
}

// ---------------- GEMM2: parts[slot] = p * (h @ wo) in bf16; blocked-panel wot ----------------
__global__ __launch_bounds__(512, 4) void gemm2_kernel(const __hip_bfloat16* __restrict__ h,
                                                       const __hip_bfloat16* __restrict__ wot,
                                                       const int* __restrict__ ctrl,
                                                       const float* __restrict__ slot_prob,
                                                       __hip_bfloat16* __restrict__ parts) {
  int lin = blockIdx.x;                         // 640 = 8 * 80
  int logical = (lin & 7) * 80 + (lin >> 3);
  int mt = logical % 40;
  int ey = logical / 40;                        // 0..15
  if (mt >= ctrl[24]) return;
  int e = ctrl[32 + mt];
  int slot0 = ctrl[96 + mt];
  int rowsv = ctrl[160 + mt];
  int e0 = ey * 64;

  __shared__ alignas(16) short lA[128 * 64];
  __shared__ alignas(16) short lB[64 * 64];

  int tid = threadIdx.x;
  int w = tid >> 6, l = tid & 63;
  int wm = w >> 1, wn = w & 1;
  int frow = l & 15, fk = l >> 4;

  int r1 = tid >> 3;
  int kc = ((tid & 7) ^ (r1 & 7)) * 8;
  const __hip_bfloat16* aS1 = h + (size_t)(slot0 + r1) * F_DIM + kc;
  const __hip_bfloat16* aS2 = aS1 + (size_t)64 * F_DIM;
  const __hip_bfloat16* bS = wot + (size_t)e * E_DIM * F_DIM + (e0 + r1) * 64 + kc;

  f32x4 zero4 = {0.f, 0.f, 0.f, 0.f};
  f32x4 acc[2][2];
#pragma unroll
  for (int mi = 0; mi < 2; mi++)
#pragma unroll
    for (int ni = 0; ni < 2; ni++) acc[mi][ni] = zero4;

  auto stage = [&](int t) {
    int k0 = t * 64;
    gload_lds16(aS1 + k0, &lA[w * 512]);
    gload_lds16(aS2 + k0, &lA[4096 + w * 512]);
    gload_lds16(bS + (size_t)t * (E_DIM * 64), &lB[w * 512]);
  };

  const int NT = F_DIM / 64;
  for (int t = 0; t < NT; ++t) {
    if (t) __syncthreads();
    stage(t);
    __syncthreads();
    __builtin_amdgcn_s_setprio(1);
#pragma unroll
    for (int ks = 0; ks < 2; ++ks) {
      short8 a[2], b[2];
#pragma unroll
      for (int mi = 0; mi < 2; ++mi) {
        int r = wm * 32 + mi * 16 + frow;
        a[mi] = *(const short8*)&lA[r * 64 + ((ks * 4 + fk) ^ (r & 7)) * 8];
      }
#pragma unroll
      for (int ni = 0; ni < 2; ++ni) {
        int n = wn * 32 + ni * 16 + frow;
        b[ni] = *(const short8*)&lB[n * 64 + ((ks * 4 + fk) ^ (n & 7)) * 8];
      }
#pragma unroll
      for (int mi = 0; mi < 2; ++mi)
#pragma unroll
        for (int ni = 0; ni < 2; ++ni)
          acc[mi][ni] = __builtin_amdgcn_mfma_f32_16x16x32_bf16(a[mi], b[ni], acc[mi][ni], 0, 0, 0);
    }
    __builtin_amdgcn_s_setprio(0);
  }

#pragma unroll
  for (int mi = 0; mi < 2; ++mi) {
#pragma unroll
    for (int j = 0; j < 4; ++j) {
      int r = wm * 32 + mi * 16 + fk * 4 + j;
      if (r < rowsv) {
        int slot = slot0 + r;
        float p = slot_prob[slot];
        __hip_bfloat16* pr = parts + (size_t)slot * E_DIM + e0 + wn * 32;
#pragma unroll
        for (int ni = 0; ni < 2; ++ni)
          pr[ni * 16 + frow] = __float2bfloat16(p * acc[mi][ni][j]);
      }
    }
  }
}

// ---------------- combine: out[t] = parts[s1] + parts[s2] (bf16 parts -> fp32 out) ----------------
__global__ __launch_bounds__(256) void combine_kernel(const __hip_bfloat16* __restrict__ parts,
                                                      const int* __restrict__ inv,
                                                      float* __restrict__ out) {
  int g = blockIdx.x * 256 + threadIdx.x;   // T_TOK*128
  int row = g >> 7, c = (g & 127) * 8;
  int s1 = inv[row * 2], s2 = inv[row * 2 + 1];
  short8 p1 = *(const short8*)(parts + (size_t)s1 * E_DIM + c);
  short8 p2 = *(const short8*)(parts + (size_t)s2 * E_DIM + c);
  float o[8];
#pragma unroll
  for (int j = 0; j < 8; ++j) {
    union { short s; __hip_bfloat16 b; } u1, u2;
    u1.s = p1[j]; u2.s = p2[j];
    o[j] = __bfloat162float(u1.b) + __bfloat162float(u2.b);
  }
  float4* op = (float4*)(out + (size_t)row * E_DIM + c);
  op[0] = make_float4(o[0], o[1], o[2], o[3]);
  op[1] = make_float4(o[4], o[5], o[6], o[7]);
}

extern "C" void kernel_launch(void* const* d_in, const int* in_sizes, int n_in,
                              void* d_out, int out_size, void* d_ws, size_t ws_size,
                              hipStream_t stream) {
  const float* x  = (const float*)d_in[0];
  const float* gk = (const float*)d_in[1];
  const float* w0 = (const float*)d_in[2];
  const float* w1 = (const float*)d_in[3];
  const float* wo = (const float*)d_in[4];
  float* out = (float*)d_out;
  char* ws = (char*)d_ws;

  const size_t SLOTS = 2 * T_TOK + 128;
  const size_t OFF_XB   = 0;
  const size_t OFF_W0T  = OFF_XB  + (size_t)T_TOK * E_DIM * 2;
  const size_t OFF_W1T  = OFF_W0T + (size_t)N_EXP * E_DIM * F_DIM * 2;
  const size_t OFF_WOT  = OFF_W1T + (size_t)N_EXP * E_DIM * F_DIM * 2;
  const size_t OFF_H    = OFF_WOT + (size_t)N_EXP * F_DIM * E_DIM * 2;
  const size_t OFF_STOK = OFF_H   + SLOTS * F_DIM * 2;
  const size_t OFF_SPRB = OFF_STOK + SLOTS * 4;
  const size_t OFF_TKE  = OFF_SPRB + SLOTS * 4;
  const size_t OFF_TKP  = OFF_TKE + (size_t)2 * T_TOK * 4;
  const size_t OFF_INV  = OFF_TKP + (size_t)2 * T_TOK * 4;
  const size_t OFF_CTRL = OFF_INV + (size_t)2 * T_TOK * 4;
  const size_t NEED     = OFF_CTRL + 1024;
  if (ws_size < NEED) return;

  __hip_bfloat16* xb   = (__hip_bfloat16*)(ws + OFF_XB);
  __hip_bfloat16* w0t  = (__hip_bfloat16*)(ws + OFF_W0T);
  __hip_bfloat16* w1t  = (__hip_bfloat16*)(ws + OFF_W1T);
  __hip_bfloat16* wot  = (__hip_bfloat16*)(ws + OFF_WOT);
  __hip_bfloat16* hbuf = (__hip_bfloat16*)(ws + OFF_H);
  __hip_bfloat16* parts = (__hip_bfloat16*)(ws + OFF_W0T);  // alias: w0t dead after gemm1
  int*   slot_tok  = (int*)(ws + OFF_STOK);
  float* slot_prob = (float*)(ws + OFF_SPRB);
  int*   tk_e      = (int*)(ws + OFF_TKE);
  float* tk_p      = (float*)(ws + OFF_TKP);
  int*   inv       = (int*)(ws + OFF_INV);
  int*   ctrl      = (int*)(ws + OFF_CTRL);

  hipMemsetAsync(ctrl, 0, 1024, stream);
  hipMemsetAsync(slot_tok + 2 * T_TOK, 0, 128 * 4, stream);

  prep3d_kernel<<<dim3(32, 16, 18), 256, 0, stream>>>(w0, w1, x, gk, w0t, w1t, xb, tk_e, tk_p, ctrl);
  scanperm_kernel<<<1, 256, 0, stream>>>(tk_e, tk_p, ctrl, slot_tok, slot_prob, inv);
  gemm1_kernel<<<3328, 512, 0, stream>>>(xb, w0t, w1t, ctrl, slot_tok, hbuf, wo, wot);
  gemm2_kernel<<<640, 512, 0, stream>>>(hbuf, wot, ctrl, slot_prob, parts);
  combine_kernel<<<(T_TOK * 128) / 256, 256, 0, stream>>>(parts, inv, out);
}